// Round 16
// baseline (231.893 us; speedup 1.0000x reference)
//
#include <hip/hip_runtime.h>

#define N_NODES 50000
#define N_EDGES 800000
#define D 64
#define COARSE 196           // coarse bins of 256 nodes (tgt>>8)
#define SHARDS 16            // reservation shards per bin (block b -> b&15)
#define SCAP 384             // per (bin,shard) capacity: mean 255 + 8 sigma
#define BINS 3125            // k2 bins of 16 nodes
#define BIN_NODES 16
#define NODE_CAP 64          // deg ~ Poisson(16); P(>64) ~ 1e-18
#define BROW 72              // u16 stride per node bucket in LDS (144 B)
#define KA_BLOCKS 391        // 2048 edges per block (1024 threads, 2 edges/thr)
#define KA_EDGES 2048
#define CVT_BLOCKS 3125
#define GEMV_BLOCKS 3125
#define MID_BLOCKS (CVT_BLOCKS + GEMV_BLOCKS)

__device__ __forceinline__ unsigned int f2bf(float f) {
    unsigned int u = __builtin_bit_cast(unsigned int, f);
    return (u + 0x7fffu + ((u >> 16) & 1u)) >> 16;
}
__device__ __forceinline__ float bflo(unsigned int v) {
    return __builtin_bit_cast(float, v << 16);
}
__device__ __forceinline__ float bfhi(unsigned int v) {
    return __builtin_bit_cast(float, v & 0xffff0000u);
}

// ---------------------------------------------------------------------------
// KA: coarse binning. 1024-thread blocks (16 waves/block, ~24 waves/CU -- was
// 6) so the phase-3 scatter latency chains overlap. Each thread owns 2 edges
// held in REGISTERS across the barriers (no LDS staging, no L2 re-read).
// ---------------------------------------------------------------------------
__global__ __launch_bounds__(1024) void ka_kernel(
        const int* __restrict__ src, const int* __restrict__ tgt,
        int* __restrict__ gCur, unsigned int* __restrict__ gPairs) {
    __shared__ int hist[COARSE], rbase[COARSE], cur2[COARSE];
    int b = blockIdx.x;
    int tid = threadIdx.x;
    int eb = b * KA_EDGES;
    int n = N_EDGES - eb; if (n > KA_EDGES) n = KA_EDGES;
    int shard = b & (SHARDS - 1);
    if (tid < COARSE) { hist[tid] = 0; cur2[tid] = 0; }
    __syncthreads();

    // phase 1: load 2 edges into registers + histogram
    unsigned int p0 = 0, p1 = 0;
    int i0 = tid * 2;
    bool v = i0 < n;                 // pairs are 2-aligned; n even except tail
    if (v) {
        uint2 tv = *(const uint2*)(tgt + eb + i0);
        uint2 sv = *(const uint2*)(src + eb + i0);
        p0 = (tv.x << 16) | sv.x;
        p1 = (tv.y << 16) | sv.y;
        atomicAdd(&hist[tv.x >> 8], 1);
        atomicAdd(&hist[tv.y >> 8], 1);
    }
    __syncthreads();
    // phase 2: sharded global reservation
    if (tid < COARSE && hist[tid] > 0)
        rbase[tid] = atomicAdd(&gCur[tid * SHARDS + shard], hist[tid]);
    __syncthreads();
    // phase 3: scatter the 2 register-held pairs
    if (v) {
        size_t segBase = (size_t)shard * SCAP;
        int c0 = p0 >> 24;
        int pos0 = rbase[c0] + atomicAdd(&cur2[c0], 1);
        if (pos0 < SCAP)
            gPairs[(size_t)c0 * (SHARDS * SCAP) + segBase + pos0] = p0;
        int c1 = p1 >> 24;
        int pos1 = rbase[c1] + atomicAdd(&cur2[c1], 1);
        if (pos1 < SCAP)
            gPairs[(size_t)c1 * (SHARDS * SCAP) + segBase + pos1] = p1;
    }
}

// ---------------------------------------------------------------------------
// MID: cvt + gemv ONLY (pure streaming ~45 MB -- model says 15-20 us; if this
// still reads ~58 us the ~57 us per-dispatch pattern is systemic, not work).
//  [0, CVT):    data16 = bf16(data), RNE, coalesced.
//  [CVT,+GEMV): out = merge @ W_tr^T + b_tr  (direct to d_out; k2 RMWs it)
// ---------------------------------------------------------------------------
__global__ __launch_bounds__(256) void mid_kernel(
        const float* __restrict__ data,
        const float* __restrict__ merge,
        const float* __restrict__ W_tr, const float* __restrict__ b_tr,
        unsigned short* __restrict__ data16,
        float* __restrict__ outv) {
    int b = blockIdx.x;
    int tid = threadIdx.x;
    if (b < CVT_BLOCKS) {
        int i = b * 256 + tid;                   // float4 index
        float4 d = ((const float4*)data)[i];
        uint2 v;
        v.x = f2bf(d.x) | (f2bf(d.y) << 16);
        v.y = f2bf(d.z) | (f2bf(d.w) << 16);
        ((uint2*)data16)[i] = v;
    } else {
        int gb = b - CVT_BLOCKS;
        int lane = tid & 63;
        int slot = tid >> 6;
        float4 Wr[16];
        const float4* wrow = (const float4*)(W_tr + (size_t)lane * D);
#pragma unroll
        for (int i = 0; i < 16; i++) Wr[i] = wrow[i];
        float bias = b_tr[lane];
        const int stride = GEMV_BLOCKS * 4;
        int r = gb * 4 + slot;
        float rv = merge[(size_t)r * D + lane];
        while (r < N_NODES) {
            int rn = r + stride;
            float rv_next = 0.f;
            if (rn < N_NODES) rv_next = merge[(size_t)rn * D + lane];
            float a0 = 0.f, a1 = 0.f, a2 = 0.f, a3 = 0.f;
#pragma unroll
            for (int i = 0; i < 16; i++) {
                a0 += __shfl(rv, 4 * i)     * Wr[i].x;
                a1 += __shfl(rv, 4 * i + 1) * Wr[i].y;
                a2 += __shfl(rv, 4 * i + 2) * Wr[i].z;
                a3 += __shfl(rv, 4 * i + 3) * Wr[i].w;
            }
            outv[(size_t)r * D + lane] = ((a0 + a1) + (a2 + a3)) + bias;
            rv = rv_next;
            r = rn;
        }
    }
}

// ---------------------------------------------------------------------------
// K2: one block per 16-node bin. FILL IS MERGED IN: the block sweeps its
// coarse bin's 16 shard segments and filters the 1/16 of pairs belonging to
// it straight into LDS buckets (R12-verified path; srcs16/deg round-trip
// deleted). Then the known-good gather + fused GEMV.
// ---------------------------------------------------------------------------
__global__ __launch_bounds__(256) void k2_kernel(
        const float* __restrict__ data,
        const unsigned short* __restrict__ data16,
        const int* __restrict__ gCur,
        const unsigned int* __restrict__ gPairs,
        const float* __restrict__ W_lin,
        float* __restrict__ out) {
    __shared__ __align__(16) unsigned short lbkt[BIN_NODES * BROW];
    __shared__ int lcur[BIN_NODES];
    __shared__ int cnts[SHARDS];
    __shared__ float hbuf[BIN_NODES * D];

    int tid = threadIdx.x;
    int lane = tid & 63;
    int f = blockIdx.x;                  // fine bin
    int c = f >> 4;                      // coarse bin
    int fl = f & 15;                     // fine index within coarse
    int nodeBase = f * BIN_NODES;

    float4 Wr[16];
    const float4* wrow = (const float4*)(W_lin + (size_t)lane * D);
#pragma unroll
    for (int i = 0; i < 16; i++) Wr[i] = wrow[i];

    if (tid < BIN_NODES) lcur[tid] = 0;
    if (tid >= 32 && tid < 32 + SHARDS) {
        int cnt = gCur[c * SHARDS + (tid - 32)];
        cnts[tid - 32] = cnt > SCAP ? SCAP : cnt;
    }
    __syncthreads();

    const unsigned int* cbase = gPairs + (size_t)c * (SHARDS * SCAP);
    for (int s = 0; s < SHARDS; s++) {
        int cnt = cnts[s];
        const unsigned int* cp = cbase + (size_t)s * SCAP;
        for (int i = tid; i < cnt; i += 256) {
            unsigned int p = cp[i];
            if ((int)((p >> 20) & 15) == fl) {
                int tl = (p >> 16) & 15;
                int pos = atomicAdd(&lcur[tl], 1);
                if (pos < NODE_CAP)
                    lbkt[tl * BROW + pos] = (unsigned short)(p & 0xffffu);
            }
        }
    }
    __syncthreads();

    int G = tid >> 3;
    int ln = tid & 7;
    int node = G >> 1;
    int par = G & 1;
    int n = nodeBase + node;
    int dg = lcur[node];
    int dgc = dg < NODE_CAP ? dg : NODE_CAP;

    const float4* orow = (const float4*)(data + (size_t)n * D + 8 * ln);
    float4 o0 = orow[0], o1 = orow[1];

    float a0[8] = {0,0,0,0,0,0,0,0}, a1[8] = {0,0,0,0,0,0,0,0};
    float a2[8] = {0,0,0,0,0,0,0,0}, a3[8] = {0,0,0,0,0,0,0,0};
    const uint2* idxp = (const uint2*)(lbkt + node * BROW + par * 4);
    int nIt = (dgc + 7) >> 3;
    for (int it = 0; it < nIt; it++) {
        uint2 iw = idxp[it * 2];
        int e0 = it * 8 + par * 4;
        unsigned int i0 = iw.x & 0xffffu, i1 = iw.x >> 16;
        unsigned int i2 = iw.y & 0xffffu, i3 = iw.y >> 16;
        if (e0 < dgc) {
            uint4 v2 = *(const uint4*)(data16 + (size_t)i0 * D + 8 * ln);
            a0[0] += bflo(v2.x); a0[1] += bfhi(v2.x); a0[2] += bflo(v2.y); a0[3] += bfhi(v2.y);
            a0[4] += bflo(v2.z); a0[5] += bfhi(v2.z); a0[6] += bflo(v2.w); a0[7] += bfhi(v2.w);
        }
        if (e0 + 1 < dgc) {
            uint4 v2 = *(const uint4*)(data16 + (size_t)i1 * D + 8 * ln);
            a1[0] += bflo(v2.x); a1[1] += bfhi(v2.x); a1[2] += bflo(v2.y); a1[3] += bfhi(v2.y);
            a1[4] += bflo(v2.z); a1[5] += bfhi(v2.z); a1[6] += bflo(v2.w); a1[7] += bfhi(v2.w);
        }
        if (e0 + 2 < dgc) {
            uint4 v2 = *(const uint4*)(data16 + (size_t)i2 * D + 8 * ln);
            a2[0] += bflo(v2.x); a2[1] += bfhi(v2.x); a2[2] += bflo(v2.y); a2[3] += bfhi(v2.y);
            a2[4] += bflo(v2.z); a2[5] += bfhi(v2.z); a2[6] += bflo(v2.w); a2[7] += bfhi(v2.w);
        }
        if (e0 + 3 < dgc) {
            uint4 v2 = *(const uint4*)(data16 + (size_t)i3 * D + 8 * ln);
            a3[0] += bflo(v2.x); a3[1] += bfhi(v2.x); a3[2] += bflo(v2.y); a3[3] += bfhi(v2.y);
            a3[4] += bflo(v2.z); a3[5] += bfhi(v2.z); a3[6] += bflo(v2.w); a3[7] += bfhi(v2.w);
        }
    }
    float s[8];
#pragma unroll
    for (int k = 0; k < 8; k++) s[k] = (a0[k] + a1[k]) + (a2[k] + a3[k]);
#pragma unroll
    for (int k = 0; k < 8; k++) s[k] += __shfl_xor(s[k], 8);

    if (par == 0) {
        float inv = dg > 0 ? 1.0f / (float)dg : 0.0f;
        float msk = dg > 0 ? 1.0f : 0.0f;
        float4 h0, h1;
        h0.x = (o0.x - s[0] * inv) * msk; h0.y = (o0.y - s[1] * inv) * msk;
        h0.z = (o0.z - s[2] * inv) * msk; h0.w = (o0.w - s[3] * inv) * msk;
        h1.x = (o1.x - s[4] * inv) * msk; h1.y = (o1.y - s[5] * inv) * msk;
        h1.z = (o1.z - s[6] * inv) * msk; h1.w = (o1.w - s[7] * inv) * msk;
        float4* hp = (float4*)(hbuf + node * D + 8 * ln);
        hp[0] = h0; hp[1] = h1;
    }
    __syncthreads();

    int w = tid >> 6;
#pragma unroll
    for (int tg = 0; tg < 4; tg++) {
        int t = w * 4 + tg;
        const float4* hrow = (const float4*)(hbuf + t * D);
        float acc = 0.f;
#pragma unroll
        for (int i = 0; i < 16; i++) {
            float4 hq = hrow[i];
            acc += hq.x * Wr[i].x + hq.y * Wr[i].y
                 + hq.z * Wr[i].z + hq.w * Wr[i].w;
        }
        int nn = nodeBase + t;
        float o = acc + out[(size_t)nn * D + lane];
        out[(size_t)nn * D + lane] = o > 0.f ? o : 0.f;
    }
}

extern "C" void kernel_launch(void* const* d_in, const int* in_sizes, int n_in,
                              void* d_out, int out_size, void* d_ws, size_t ws_size,
                              hipStream_t stream) {
    const float* data  = (const float*)d_in[0];
    const float* merge = (const float*)d_in[1];
    const int*   src   = (const int*)d_in[2];
    const int*   tgt   = (const int*)d_in[3];
    // d_in[4]=W_lin, d_in[5]=b_lin (cancels in lap), d_in[6]=W_tr, d_in[7]=b_tr
    const float* W_lin = (const float*)d_in[4];
    const float* W_tr  = (const float*)d_in[6];
    const float* b_tr  = (const float*)d_in[7];
    float* out = (float*)d_out;

    // Workspace: gCur[196*16 i32] | gPairs[196*16*384 u32] (4.8 MB)
    //            | data16[N*D bf16] (6.4 MB)            total ~11.2 MB
    char* ws = (char*)d_ws;
    size_t o = 0;
    int*            gCur   = (int*)(ws + o);            o += (size_t)COARSE * SHARDS * 4;
    unsigned int*   gPairs = (unsigned int*)(ws + o);   o += (size_t)COARSE * SHARDS * SCAP * 4;
    unsigned short* data16 = (unsigned short*)(ws + o); o += (size_t)N_NODES * D * 2;

    hipMemsetAsync(gCur, 0, (size_t)COARSE * SHARDS * 4, stream);

    ka_kernel<<<KA_BLOCKS, 1024, 0, stream>>>(src, tgt, gCur, gPairs);

    mid_kernel<<<MID_BLOCKS, 256, 0, stream>>>(
        data, merge, W_tr, b_tr, data16, out);

    k2_kernel<<<BINS, 256, 0, stream>>>(
        data, data16, gCur, gPairs, W_lin, out);
}